// Round 2
// baseline (177.435 us; speedup 1.0000x reference)
//
#include <hip/hip_runtime.h>
#include <hip/hip_bf16.h>
#include <hip/hip_cooperative_groups.h>

namespace cg = cooperative_groups;

typedef __attribute__((ext_vector_type(4))) float f32x4;
typedef __attribute__((ext_vector_type(8))) short bf16x8;
typedef unsigned int u32;
typedef unsigned short u16;

#define DEV static __device__ __forceinline__

// T=32,B=32 -> TB=1024 ; N=64 ; D=1024 ; H=16 ; HD=64
// d_out: attended [1024x1024] f32 @0 ; mean_attn [1024x64] @1048576 ; logits [1024x16x64] @1114112

DEV u16 f2bf(float x){                       // RNE f32->bf16
  union { float f; u32 u; } v; v.f = x;
  u32 r = v.u + 0x7FFFu + ((v.u >> 16) & 1u);
  return (u16)(r >> 16);
}
DEV float bf2f(u16 s){
  union { u32 u; float f; } v; v.u = ((u32)s) << 16;
  return v.f;
}

#define MFMA16(a,b,c) __builtin_amdgcn_mfma_f32_16x16x32_bf16((a),(b),(c),0,0,0)

DEV int tok_off(int n, int dbyte){ return n*2048 + (dbyte ^ ((n & 7) << 4)); }

// ============================ MEGA (cooperative) path ============================
// Dynamic LDS: 64KB = TWO 32KB token buffers (16 tokens each, double-buffered).
// Scratch lives in a 10.25KB static overlay. 74.25KB/block -> 2/CU.
#define MEGA_DYN_LDS 65536

__global__ __launch_bounds__(256, 2) void k_mega(
    const float* __restrict__ qv, const float* __restrict__ tokens,
    const float* __restrict__ gate,
    const float* __restrict__ Wq, const float* __restrict__ bq,
    const float* __restrict__ Wk, const float* __restrict__ bk,
    const float* __restrict__ Wv, const float* __restrict__ bv,
    u16* __restrict__ qvB, u16* __restrict__ WqT, u16* __restrict__ WkB,
    u16* __restrict__ WvT, float* __restrict__ qf, u16* __restrict__ qb,
    u16* __restrict__ U, u16* __restrict__ ctxb,
    float* __restrict__ out_att, float* __restrict__ out_mean,
    float* __restrict__ out_logits){
  extern __shared__ __align__(16) char smem[];        // 2 x 32KB token buffers
  __shared__ __align__(16) char sstat[10496];         // static scratch overlay
  cg::grid_group grid = cg::this_grid();
  const int tid = threadIdx.x;
  const int bx  = blockIdx.x;                 // 0..511
  const int l = tid & 63, w = tid >> 6, g = l >> 4, li = l & 15;

  // ================= P0: qv -> bf16 ; weights -> bf16 (WqT,WvT transposed; Wk plain) ======
  {
    const f32x4* s4 = (const f32x4*)qv;
    uint2* d2 = (uint2*)qvB;
    int g0 = bx*256 + tid;
    #pragma unroll
    for (int i = 0; i < 2; ++i){
      int idx = g0 + i*131072;
      f32x4 v = s4[idx];
      uint2 pk;
      pk.x = (u32)f2bf(v.x) | ((u32)f2bf(v.y) << 16);
      pk.y = (u32)f2bf(v.z) | ((u32)f2bf(v.w) << 16);
      d2[idx] = pk;
    }
  }
  {
    u16 (*tile)[65] = (u16 (*)[65])sstat;             // 8320B <= 10496
    for (int tl = bx; tl < 768; tl += 512){
      __syncthreads();
      const int which = tl >> 8, t8 = tl & 255;
      const float* src = which==0 ? Wq : (which==1 ? Wk : Wv);
      const int bi = (t8 >> 4) << 6, bj = (t8 & 15) << 6;
      #pragma unroll
      for (int k2 = 0; k2 < 16; ++k2){
        int e = tid + (k2 << 8); int r = e >> 6, c = e & 63;
        tile[r][c] = f2bf(src[(size_t)(bi + r)*1024 + bj + c]);
      }
      __syncthreads();
      if (which == 1){
        #pragma unroll
        for (int k2 = 0; k2 < 16; ++k2){
          int e = tid + (k2 << 8); int r = e >> 6, c = e & 63;
          WkB[(size_t)(bi + r)*1024 + bj + c] = tile[r][c];
        }
      } else {
        u16* dst = which==0 ? WqT : WvT;
        #pragma unroll
        for (int k2 = 0; k2 < 16; ++k2){
          int e = tid + (k2 << 8); int r = e >> 6, c = e & 63;
          dst[(size_t)(bj + r)*1024 + bi + c] = tile[c][r];
        }
      }
    }
  }
  __threadfence(); grid.sync(); __threadfence();

  // ================= P1: q = qvB @ WqT + bq ; 512 tiles 64x32 =============================
  {
    const int wm = w & 1, wn = w >> 1;
    const int m_base = (bx >> 5)*64 + wm*32;
    const int n_base = (bx & 31)*32 + wn*16;
    f32x4 acc[2]; acc[0] = (f32x4)0.0f; acc[1] = (f32x4)0.0f;
    #pragma unroll 4
    for (int kb = 0; kb < 32; ++kb){
      const int k0 = kb*32 + g*8;
      bf16x8 b = *(const bf16x8*)(WqT + (size_t)(n_base + li)*1024 + k0);
      #pragma unroll
      for (int rt = 0; rt < 2; ++rt){
        bf16x8 a = *(const bf16x8*)(qvB + (size_t)(m_base + rt*16 + li)*1024 + k0);
        acc[rt] = MFMA16(a, b, acc[rt]);
      }
    }
    #pragma unroll
    for (int rt = 0; rt < 2; ++rt)
      #pragma unroll
      for (int r = 0; r < 4; ++r){
        int m = m_base + rt*16 + g*4 + r;     // C/D map: row=(lane>>4)*4+reg, col=lane&15
        int n = n_base + li;
        float val = acc[rt][r] + bq[n];
        qf[(size_t)m*1024 + n] = val;
        qb[(size_t)m*1024 + n] = f2bf(val);
      }
  }
  __threadfence(); grid.sync(); __threadfence();

  // ================= P2: U[tb][h][d] = q[tb][hslice] . Wk[d][hslice] ; 8 tiles/block ======
  {
    u16 (*stile)[64] = (u16 (*)[64])sstat;            // 8192B
    const int wm = w & 1, wn = w >> 1;
    for (int i = 0; i < 8; ++i){
      const int tl = bx*8 + i;
      const int tb0 = (tl >> 8)*64, d0 = ((tl >> 4) & 15)*64, h = tl & 15;
      f32x4 acc[2][2];
      #pragma unroll
      for (int a0=0;a0<2;++a0)
        #pragma unroll
        for (int b0=0;b0<2;++b0) acc[a0][b0] = (f32x4)0.0f;
      #pragma unroll
      for (int kb = 0; kb < 2; ++kb){
        const int k0 = h*64 + kb*32 + g*8;
        bf16x8 a[2], b[2];
        #pragma unroll
        for (int rt=0;rt<2;++rt)
          a[rt] = *(const bf16x8*)(qb + (size_t)(tb0 + wm*32 + rt*16 + li)*1024 + k0);
        #pragma unroll
        for (int ct=0;ct<2;++ct)
          b[ct] = *(const bf16x8*)(WkB + (size_t)(d0 + wn*32 + ct*16 + li)*1024 + k0);
        #pragma unroll
        for (int rt=0;rt<2;++rt)
          #pragma unroll
          for (int ct=0;ct<2;++ct)
            acc[rt][ct] = MFMA16(a[rt], b[ct], acc[rt][ct]);
      }
      __syncthreads();
      #pragma unroll
      for (int rt=0;rt<2;++rt)
        #pragma unroll
        for (int ct=0;ct<2;++ct)
          #pragma unroll
          for (int r=0;r<4;++r)
            stile[wm*32 + rt*16 + g*4 + r][wn*32 + ct*16 + li] = f2bf(acc[rt][ct][r]);
      __syncthreads();
      const int rr = tid >> 2, cg4 = tid & 3;
      f32x4* dst = (f32x4*)(U + ((size_t)(tb0 + rr)*16 + h)*1024 + d0 + cg4*16);
      const f32x4* s4 = (const f32x4*)(&stile[rr][cg4*16]);
      dst[0] = s4[0]; dst[1] = s4[1];
    }
  }
  __threadfence(); grid.sync(); __threadfence();

  // ================= P3: fused attention, double-buffered 16-token rounds =================
  // 8 rounds = 2 tb x 4 chunks of 16 tokens. Round r computes from buf[r&1] while round
  // r+1's tokens are loaded (issued at round top, pinned by sched_barrier) and written to
  // buf[(r+1)&1] at round bottom -- no barrier between staging write and current compute.
  // U a-frags (a[8], 32 VGPR) hoisted per-tb; staging stg[16] = 64 VGPR (fits, no sink).
  {
    float* part_s   = (float*)(sstat);          // [4][64][4] 4096B
    float* logits_s = (float*)(sstat + 4096);   // [16][64]   4096B
    float* p_s      = (float*)(sstat + 8192);   // [16][16]   1024B
    float* csum     = (float*)(sstat + 10240);  // [16]
    float* r_s      = (float*)(sstat + 10304);  // [16]
    float* mzs      = (float*)(sstat + 10368);  // [16][2]
    const int sh = tid >> 4, sj = tid & 15;

    __syncthreads();                            // P2's stile readers done before overlay reuse

    // ---- prologue: stage chunk 0 (tb=bx, n=0..15) into buf0 ----
    {
      const f32x4* src4 = (const f32x4*)(tokens + (size_t)bx*65536);
      f32x4 pstg[16];
      #pragma unroll
      for (int it = 0; it < 16; ++it) pstg[it] = src4[(size_t)it*256 + tid];
      #pragma unroll
      for (int it = 0; it < 16; ++it){
        f32x4 v = pstg[it];
        uint2 pk;
        pk.x = (u32)f2bf(v.x) | ((u32)f2bf(v.y) << 16);
        pk.y = (u32)f2bf(v.z) | ((u32)f2bf(v.w) << 16);
        *(uint2*)(smem + tok_off(it, tid*8)) = pk;
      }
    }

    float m_run = -1e30f, z_run = 0.0f;
    f32x4 cacc[4][4];
    bf16x8 a[8];                                // per-tb A-fragments (round-invariant)

    for (int r = 0; r < 8; ++r){
      const int c = r & 3, n0 = c*16;
      const int tb = bx + (r >> 2)*512;
      char* bufc = smem + (size_t)(r & 1)*32768;

      // ---- issue next chunk's token loads ASAP (T14 async-STAGE, issue-early) ----
      f32x4 stg[16];
      const int rn = r + 1;
      if (rn < 8){
        const f32x4* srcn = (const f32x4*)(tokens
            + (size_t)(bx + (rn >> 2)*512)*65536 + (size_t)((rn & 3)*16)*1024);
        #pragma unroll
        for (int it = 0; it < 16; ++it)
          stg[it] = srcn[(size_t)it*256 + tid];
        __builtin_amdgcn_sched_barrier(0);      // pin: loads stay issued above compute
      }
      __builtin_amdgcn_sched_barrier(0);

      if (c == 0){
        m_run = -1e30f; z_run = 0.0f;
        #pragma unroll
        for (int i=0;i<4;++i)
          #pragma unroll
          for (int j=0;j<4;++j) cacc[i][j] = (f32x4)0.0f;
        const bf16x8* Ub = (const bf16x8*)(U + (size_t)tb*16384);
        #pragma unroll
        for (int i = 0; i < 8; ++i)
          a[i] = Ub[li*128 + (w*8 + i)*4 + g];
        // csum[h] = q[tb, h*64:] . bk[h*64:]
        const float* qp = qf + (size_t)tb*1024 + sh*64 + sj*4;
        const float* bp = bk + sh*64 + sj*4;
        float part = qp[0]*bp[0] + qp[1]*bp[1] + qp[2]*bp[2] + qp[3]*bp[3];
        part += __shfl_xor(part, 1); part += __shfl_xor(part, 2);
        part += __shfl_xor(part, 4); part += __shfl_xor(part, 8);
        if (sj == 0) csum[sh] = part;
      }

      __syncthreads();                          // (A) buf[r&1] writes + csum visible

      // ---- QK^T: each wave takes K-slice w*256..+255 (8 MFMAs), 4-way reduce ----
      {
        f32x4 acc = (f32x4)0.0f;
        #pragma unroll
        for (int i = 0; i < 8; ++i){
          bf16x8 b = *(const bf16x8*)(bufc + tok_off(li, ((w*8 + i)*32 + g*8)*2));
          acc = MFMA16(a[i], b, acc);
        }
        *(f32x4*)(part_s + (size_t)(w*64 + l)*4) = acc;
        __syncthreads();                        // (B)
        if (w == 0){
          acc += *(const f32x4*)(part_s + (size_t)(64  + l)*4);
          acc += *(const f32x4*)(part_s + (size_t)(128 + l)*4);
          acc += *(const f32x4*)(part_s + (size_t)(192 + l)*4);
          float gv = gate[(size_t)tb*64 + n0 + li];
          #pragma unroll
          for (int rg = 0; rg < 4; ++rg){
            int h = g*4 + rg;
            logits_s[h*64 + n0 + li] = (acc[rg] + csum[h])*0.125f + gv;
          }
        }
        __syncthreads();                        // (C)
      }

      // ---- online softmax over the 16-n chunk (one logit per thread) ----
      {
        float lv = logits_s[sh*64 + n0 + sj];
        out_logits[(size_t)tb*1024 + sh*64 + n0 + sj] = lv;
        float cm = lv;
        cm = fmaxf(cm, __shfl_xor(cm, 1)); cm = fmaxf(cm, __shfl_xor(cm, 2));
        cm = fmaxf(cm, __shfl_xor(cm, 4)); cm = fmaxf(cm, __shfl_xor(cm, 8));
        float m_new = fmaxf(m_run, cm);
        float rsc = __expf(m_run - m_new);
        float p0 = __expf(lv - m_new);
        float zs = p0;
        zs += __shfl_xor(zs, 1); zs += __shfl_xor(zs, 2);
        zs += __shfl_xor(zs, 4); zs += __shfl_xor(zs, 8);
        z_run = z_run * rsc + zs;
        m_run = m_new;
        p_s[sj*16 + sh] = p0;
        if (sj == 0){
          r_s[sh] = rsc;
          if (c == 3){ mzs[sh*2] = m_new; mzs[sh*2 + 1] = 1.0f / z_run; }
        }
      }
      __syncthreads();                          // (D)

      // ---- PV (scalar FMA from LDS tokens, 16 nl) ----
      {
        float rr4[4];
        #pragma unroll
        for (int hh = 0; hh < 4; ++hh) rr4[hh] = r_s[w*4 + hh];
        #pragma unroll
        for (int dq = 0; dq < 4; ++dq)
          #pragma unroll
          for (int hh = 0; hh < 4; ++hh) cacc[dq][hh] *= rr4[hh];
        for (int nl = 0; nl < 16; ++nl){
          f32x4 p = *(const f32x4*)(p_s + nl*16 + w*4);
          #pragma unroll
          for (int dq = 0; dq < 4; ++dq){
            uint2 t2 = *(const uint2*)(bufc + tok_off(nl, (dq*256 + l*4)*2));
            float f0 = bf2f((u16)(t2.x & 0xFFFFu));
            float f1 = bf2f((u16)(t2.x >> 16));
            float f2 = bf2f((u16)(t2.y & 0xFFFFu));
            float f3 = bf2f((u16)(t2.y >> 16));
            #pragma unroll
            for (int hh = 0; hh < 4; ++hh){
              float av = p[hh];
              cacc[dq][hh].x += av*f0; cacc[dq][hh].y += av*f1;
              cacc[dq][hh].z += av*f2; cacc[dq][hh].w += av*f3;
            }
          }
        }
      }

      // ---- convert + write next chunk into the OTHER buffer (no barrier needed) ----
      if (rn < 8){
        char* bufn = smem + (size_t)(rn & 1)*32768;
        #pragma unroll
        for (int it = 0; it < 16; ++it){
          f32x4 v = stg[it];
          uint2 pk;
          pk.x = (u32)f2bf(v.x) | ((u32)f2bf(v.y) << 16);
          pk.y = (u32)f2bf(v.z) | ((u32)f2bf(v.w) << 16);
          *(uint2*)(bufn + tok_off(it, tid*8)) = pk;
        }
      }

      // ---- per-tb epilogue ----
      if (c == 3){
        if (tid < 64){
          float s = 0.0f;
          #pragma unroll
          for (int h = 0; h < 16; ++h)
            s += __expf(logits_s[h*64 + tid] - mzs[h*2]) * mzs[h*2 + 1];
          out_mean[(size_t)tb*64 + tid] = s * 0.0625f;
        }
        #pragma unroll
        for (int hh = 0; hh < 4; ++hh){
          const int h = w*4 + hh;
          const float zinv = mzs[h*2 + 1];
          #pragma unroll
          for (int dq = 0; dq < 4; ++dq){
            f32x4 v = cacc[dq][hh];
            uint2 pk;
            pk.x = (u32)f2bf(v.x * zinv) | ((u32)f2bf(v.y * zinv) << 16);
            pk.y = (u32)f2bf(v.z * zinv) | ((u32)f2bf(v.w * zinv) << 16);
            *(uint2*)(ctxb + ((size_t)tb*16 + h)*1024 + dq*256 + l*4) = pk;
          }
        }
      }
    }
  }
  __threadfence(); grid.sync(); __threadfence();

  // ================= P4: attended = ctx @ WvT + bv ; 512 tiles 32(m) x 64(h-cols) =========
  {
    const int wm = w & 1, wn = w >> 1;
    const int m_base = (bx >> 4)*32, h = bx & 15;
    f32x4 acc[2]; acc[0] = (f32x4)0.0f; acc[1] = (f32x4)0.0f;
    #pragma unroll 4
    for (int kb = 0; kb < 32; ++kb){
      const int k0 = kb*32 + g*8;
      bf16x8 a = *(const bf16x8*)(ctxb + ((size_t)(m_base + wm*16 + li)*16 + h)*1024 + k0);
      #pragma unroll
      for (int ct = 0; ct < 2; ++ct){
        bf16x8 b = *(const bf16x8*)(WvT + (size_t)(h*64 + wn*32 + ct*16 + li)*1024 + k0);
        acc[ct] = MFMA16(a, b, acc[ct]);
      }
    }
    #pragma unroll
    for (int ct = 0; ct < 2; ++ct)
      #pragma unroll
      for (int r = 0; r < 4; ++r){
        int m = m_base + wm*16 + g*4 + r;
        int dout = h*64 + wn*32 + ct*16 + li;
        out_att[(size_t)m*1024 + dout] = acc[ct][r] + bv[dout];
      }
  }
}

// ============================ Fallback path (round-2 proven kernels) ============================
__global__ __launch_bounds__(256) void k_convert(
    const float* __restrict__ Wq, const float* __restrict__ Wk, const float* __restrict__ Wv,
    u16* __restrict__ WqT, u16* __restrict__ WkB, u16* __restrict__ WvT){
  __shared__ u16 tile[64][65];
  const int which = blockIdx.y;
  const float* src = which==0 ? Wq : (which==1 ? Wk : Wv);
  const int bi = (blockIdx.x >> 4) << 6;
  const int bj = (blockIdx.x & 15) << 6;
  const int t  = threadIdx.x;
  #pragma unroll
  for (int k2 = 0; k2 < 16; ++k2){
    int e = t + (k2 << 8);
    int r = e >> 6, c = e & 63;
    tile[r][c] = f2bf(src[(size_t)(bi + r)*1024 + bj + c]);
  }
  __syncthreads();
  if (which == 1){
    #pragma unroll
    for (int k2 = 0; k2 < 16; ++k2){
      int e = t + (k2 << 8); int r = e >> 6, c = e & 63;
      WkB[(size_t)(bi + r)*1024 + bj + c] = tile[r][c];
    }
  } else {
    u16* dst = which==0 ? WqT : WvT;
    #pragma unroll
    for (int k2 = 0; k2 < 16; ++k2){
      int e = t + (k2 << 8); int r = e >> 6, c = e & 63;
      dst[(size_t)(bj + r)*1024 + bi + c] = tile[c][r];
    }
  }
}

__global__ __launch_bounds__(256) void k_qproj(
    const float* __restrict__ qv, const u16* __restrict__ WqT, const float* __restrict__ bq,
    float* __restrict__ qf, u16* __restrict__ qb){
  const int l = threadIdx.x & 63, w = threadIdx.x >> 6;
  const int wm = w & 1, wn = w >> 1;
  const int g = l >> 4, li = l & 15;
  const int m_base = blockIdx.x*64 + wm*32;
  const int n_base = blockIdx.y*64 + wn*32;
  f32x4 acc[2][2];
  #pragma unroll
  for (int i=0;i<2;++i)
    #pragma unroll
    for (int j=0;j<2;++j) acc[i][j] = (f32x4)0.0f;

  #pragma unroll 4
  for (int kb = 0; kb < 32; ++kb){
    const int k0 = kb*32 + g*8;
    bf16x8 a[2], b[2];
    #pragma unroll
    for (int rt = 0; rt < 2; ++rt){
      const float* p = qv + (size_t)(m_base + rt*16 + li)*1024 + k0;
      f32x4 lo = *(const f32x4*)p;
      f32x4 hi = *(const f32x4*)(p+4);
      union { u16 s[8]; bf16x8 v; } u;
      u.s[0]=f2bf(lo.x); u.s[1]=f2bf(lo.y); u.s[2]=f2bf(lo.z); u.s[3]=f2bf(lo.w);
      u.s[4]=f2bf(hi.x); u.s[5]=f2bf(hi.y); u.s[6]=f2bf(hi.z); u.s[7]=f2bf(hi.w);
      a[rt] = u.v;
    }
    #pragma unroll
    for (int ct = 0; ct < 2; ++ct)
      b[ct] = *(const bf16x8*)(WqT + (size_t)(n_base + ct*16 + li)*1024 + k0);
    #pragma unroll
    for (int rt = 0; rt < 2; ++rt)
      #pragma unroll
      for (int ct = 0; ct < 2; ++ct)
        acc[rt][ct] = MFMA16(a[rt], b[ct], acc[rt][ct]);
  }
  #pragma unroll
  for (int rt=0;rt<2;++rt)
    #pragma unroll
    for (int ct=0;ct<2;++ct)
      #pragma unroll
      for (int r=0;r<4;++r){
        int m = m_base + rt*16 + g*4 + r;
        int n = n_base + ct*16 + li;
        float val = acc[rt][ct][r] + bq[n];
        qf[(size_t)m*1024 + n] = val;
        qb[(size_t)m*1024 + n] = f2bf(val);
      }
}

__global__ __launch_bounds__(256) void k_umat(
    const u16* __restrict__ qb, const u16* __restrict__ WkB, u16* __restrict__ U){
  __shared__ __align__(16) u16 stile[64][64];
  const int l = threadIdx.x & 63, w = threadIdx.x >> 6;
  const int wm = w & 1, wn = w >> 1, g = l >> 4, li = l & 15;
  const int tb0 = blockIdx.x*64, d0 = blockIdx.y*64, h = blockIdx.z;
  f32x4 acc[2][2];
  #pragma unroll
  for (int i=0;i<2;++i)
    #pragma unroll
    for (int j=0;j<2;++j) acc[i][j] = (f32x4)0.0f;

  #pragma unroll
  for (int kb = 0; kb < 2; ++kb){
    const int k0 = h*64 + kb*32 + g*8;
    bf16x8 a[2], b[2];
    #pragma unroll
    for (int rt=0;rt<2;++rt)
      a[rt] = *(const bf16x8*)(qb + (size_t)(tb0 + wm*32 + rt*16 + li)*1024 + k0);
    #pragma unroll
    for (int ct=0;ct<2;++ct)
      b[ct] = *(const bf16x8*)(WkB + (size_t)(d0 + wn*32 + ct*16 + li)*1024 + k0);
    #pragma unroll
    for (int rt=0;rt<2;++rt)
      #pragma unroll
      for (int ct=0;ct<2;++ct)
        acc[rt][ct] = MFMA16(a[rt], b[ct], acc[rt][ct]);
  }
  #pragma unroll
  for (int rt=0;rt<2;++rt)
    #pragma unroll
    for (int ct=0;ct<2;++ct)
      #pragma unroll
      for (int r=0;r<4;++r)
        stile[wm*32 + rt*16 + g*4 + r][wn*32 + ct*16 + li] = f2bf(acc[rt][ct][r]);
  __syncthreads();
  const int r = threadIdx.x >> 2, cg4 = threadIdx.x & 3;
  f32x4* dst = (f32x4*)(U + ((size_t)(tb0 + r)*16 + h)*1024 + d0 + cg4*16);
  const f32x4* s4 = (const f32x4*)(&stile[r][cg4*16]);
  dst[0] = s4[0]; dst[1] = s4[1];
}

#define K3_LDS 76032
__global__ __launch_bounds__(256, 2) void k_attn(
    const float* __restrict__ tokens, const float* __restrict__ gate,
    const u16* __restrict__ U, const float* __restrict__ qf, const float* __restrict__ bk,
    float* __restrict__ out_logits, float* __restrict__ out_mean, u16* __restrict__ ctx){
  extern __shared__ __align__(16) char smem[];
  float* part_s   = (float*)(smem + 65536);
  float* logits_s = (float*)(smem + 69632);
  float* p_s      = (float*)(smem + 73728);
  float* csum     = (float*)(smem + 75776);
  float* r_s      = (float*)(smem + 75840);
  float* mzs      = (float*)(smem + 75904);
  const int tb = blockIdx.x;
  const int tid = threadIdx.x;
  const int l = tid & 63, w = tid >> 6, g = l >> 4, li = l & 15;
  const int nt = w & 1, kh = w >> 1;
  const int sh = tid >> 4, sj = tid & 15;

  bf16x8 a[16];
  const bf16x8* Ub = (const bf16x8*)(U + (size_t)tb*16384);
  #pragma unroll
  for (int i = 0; i < 16; ++i)
    a[i] = Ub[li*128 + (kh*16 + i)*4 + g];

  {
    const float* qp = qf + (size_t)tb*1024 + sh*64 + sj*4;
    const float* bp = bk + sh*64 + sj*4;
    float part = qp[0]*bp[0] + qp[1]*bp[1] + qp[2]*bp[2] + qp[3]*bp[3];
    part += __shfl_xor(part, 1); part += __shfl_xor(part, 2);
    part += __shfl_xor(part, 4); part += __shfl_xor(part, 8);
    if (sj == 0) csum[sh] = part;
  }

  float m_run = -1e30f, z_run = 0.0f;
  f32x4 cacc[4][4];
  #pragma unroll
  for (int i=0;i<4;++i)
    #pragma unroll
    for (int j=0;j<4;++j) cacc[i][j] = (f32x4)0.0f;

  const f32x4* src4 = (const f32x4*)(tokens + (size_t)tb*65536);

  for (int c = 0; c < 2; ++c){
    const int n0 = c*32;
    __syncthreads();
    #pragma unroll 8
    for (int it = 0; it < 32; ++it){
      f32x4 v = src4[(size_t)(n0 + it)*256 + tid];
      uint2 pk;
      pk.x = (u32)f2bf(v.x) | ((u32)f2bf(v.y) << 16);
      pk.y = (u32)f2bf(v.z) | ((u32)f2bf(v.w) << 16);
      *(uint2*)(smem + tok_off(it, tid*8)) = pk;
    }
    __syncthreads();
    {
      f32x4 acc = (f32x4)0.0f;
      #pragma unroll
      for (int i = 0; i < 16; ++i){
        int kb = kh*16 + i;
        bf16x8 b = *(const bf16x8*)(smem + tok_off(nt*16 + li, (kb*32 + g*8)*2));
        acc = MFMA16(a[i], b, acc);
      }
      *(f32x4*)(part_s + (size_t)(w*64 + l)*4) = acc;
      __syncthreads();
      if (kh == 0){
        acc += *(const f32x4*)(part_s + (size_t)((w+2)*64 + l)*4);
        float gv = gate[(size_t)tb*64 + n0 + nt*16 + li];
        #pragma unroll
        for (int r = 0; r < 4; ++r){
          int h = g*4 + r;
          logits_s[h*64 + n0 + nt*16 + li] = (acc[r] + csum[h])*0.125f + gv;
        }
      }
      __syncthreads();
    }
    {
      float lv0 = logits_s[sh*64 + n0 + sj];
      float lv1 = logits_s[sh*64 + n0 + 16 + sj];
      out_logits[(size_t)tb*1024 + sh*64 + n0 + sj]      = lv0;
      out_logits[(size_t)tb*1024 + sh*64 + n0 + 16 + sj] = lv1;
      float cm = fmaxf(lv0, lv1);
      cm = fmaxf(cm, __shfl_xor(cm, 1)); cm = fmaxf(cm, __shfl_xor(cm, 2));
      cm = fmaxf(cm, __shfl_xor(cm, 4)); cm = fmaxf(cm, __shfl_xor(cm, 8));
      float m_new = fmaxf(m_run, cm);
      float rsc = __expf(m_run - m_new);
      float p0 = __expf(lv0 - m_new), p1 = __expf(lv1 - m_new);
      float zs = p0 + p1;
      zs += __shfl_xor(zs, 1); zs += __shfl_xor(zs, 2);
      zs += __shfl_xor(zs, 4); zs += __shfl_xor(zs, 8);
      z_run = z_run * rsc + zs;
      m_run = m_new;
      p_s[sj*16 + sh]        = p0;
      p_s[(sj + 16)*16 + sh] = p1;
      if (sj == 0){
        r_s[sh] = rsc;
        if (c == 1){ mzs[sh*2] = m_new; mzs[sh*2 + 1] = 1.0f / z_run; }
      }
    }
    __syncthreads();
    {
      float rr[4];
      #pragma unroll
      for (int hh = 0; hh < 4; ++hh) rr[hh] = r_s[w*4 + hh];
      #pragma unroll
      for (int dq = 0; dq < 4; ++dq)
        #pragma unroll
        for (int hh = 0; hh < 4; ++hh) cacc[dq][hh] *= rr[hh];
      for (int nl = 0; nl < 32; ++nl){
        f32x4 p = *(const f32x4*)(p_s + nl*16 + w*4);
        #pragma unroll
        for (int dq = 0; dq < 4; ++dq){
          uint2 t2 = *(const uint2*)(smem + tok_off(nl, (dq*256 + l*4)*2));
          float f0 = bf2f((u16)(t2.x & 0xFFFFu));
          float f1 = bf2f((u16)(t2.x >> 16));
          float f2 = bf2f((u16)(t2.y & 0xFFFFu));
          float f3 = bf2f((u16)(t2.y >> 16));
          #pragma unroll
          for (int hh = 0; hh < 4; ++hh){
            float av = p[hh];
            cacc[dq][hh].x += av*f0; cacc[dq][hh].y += av*f1;
            cacc[dq][hh].z += av*f2; cacc[dq][hh].w += av*f3;
          }
        }
      }
    }
  }

  if (tid < 64){
    float s = 0.0f;
    #pragma unroll
    for (int h = 0; h < 16; ++h)
      s += __expf(logits_s[h*64 + tid] - mzs[h*2]) * mzs[h*2 + 1];
    out_mean[(size_t)tb*64 + tid] = s * 0.0625f;
  }

  #pragma unroll
  for (int hh = 0; hh < 4; ++hh){
    const int h = w*4 + hh;
    const float zinv = mzs[h*2 + 1];
    #pragma unroll
    for (int dq = 0; dq < 4; ++dq){
      f32x4 v = cacc[dq][hh];
      uint2 pk;
      pk.x = (u32)f2bf(v.x * zinv) | ((u32)f2bf(v.y * zinv) << 16);
      pk.y = (u32)f2bf(v.z * zinv) | ((u32)f2bf(v.w * zinv) << 16);
      *(uint2*)(ctx + ((size_t)tb*16 + h)*1024 + dq*256 + l*4) = pk;
    }
  }
}

__global__ __launch_bounds__(256) void k_attended(
    const u16* __restrict__ ctx, const u16* __restrict__ WvT, const float* __restrict__ bv,
    float* __restrict__ out_att){
  const int l = threadIdx.x & 63, w = threadIdx.x >> 6;
  const int wm = w & 1, wn = w >> 1, g = l >> 4, li = l & 15;
  const int tb0 = blockIdx.x*64, h = blockIdx.y;
  f32x4 acc[2][2];
  #pragma unroll
  for (int i=0;i<2;++i)
    #pragma unroll
    for (int j=0;j<2;++j) acc[i][j] = (f32x4)0.0f;

  #pragma unroll 4
  for (int kb = 0; kb < 32; ++kb){
    const int k0 = kb*32 + g*8;
    bf16x8 a[2], b[2];
    #pragma unroll
    for (int rt=0;rt<2;++rt)
      a[rt] = *(const bf16x8*)(ctx + ((size_t)(tb0 + wm*32 + rt*16 + li)*16 + h)*1024 + k0);
    #pragma unroll
    for (int ct=0;ct<2;++ct)
      b[ct] = *(const bf16x8*)(WvT + (size_t)(h*64 + wn*32 + ct*16 + li)*1024 + k0);
    #pragma unroll
    for (int rt=0;rt<2;++rt)
      #pragma unroll
      for (int ct=0;ct<2;++ct)
        acc[rt][ct] = MFMA16(a[rt], b[ct], acc[rt][ct]);
  }
  #pragma unroll
  for (int rt=0;rt<2;++rt)
    #pragma unroll
    for (int ct=0;ct<2;++ct)
      #pragma unroll
      for (int r=0;r<4;++r){
        int m = tb0 + wm*32 + rt*16 + g*4 + r;
        int dout = h*64 + wn*32 + ct*16 + li;
        out_att[(size_t)m*1024 + dout] = acc[rt][ct][r] + bv[dout];
      }
}

// ---------------- launch ----------------
extern "C" void kernel_launch(void* const* d_in, const int* in_sizes, int n_in,
                              void* d_out, int out_size, void* d_ws, size_t ws_size,
                              hipStream_t stream){
  const float* qv     = (const float*)d_in[0];
  const float* tokens = (const float*)d_in[1];
  const float* gate   = (const float*)d_in[2];
  const float* Wq     = (const float*)d_in[3];
  const float* bq     = (const float*)d_in[4];
  const float* Wk     = (const float*)d_in[5];
  const float* bk     = (const float*)d_in[6];
  const float* Wv     = (const float*)d_in[7];
  const float* bv     = (const float*)d_in[8];

  char* ws = (char*)d_ws;
  u16*   qvB = (u16*)(ws);                       // 2 MB
  u16*   WqT = (u16*)(ws + (2u<<20));            // 2 MB
  u16*   WkB = (u16*)(ws + (4u<<20));            // 2 MB
  u16*   WvT = (u16*)(ws + (6u<<20));            // 2 MB
  float* qf  = (float*)(ws + (8u<<20));          // 4 MB
  u16*   qb  = (u16*)(ws + (12u<<20));           // 2 MB
  u16*   U   = (u16*)(ws + (14u<<20));           // 32 MB
  u16*   ctxb= (u16*)(ws + (46u<<20));           // 32 MB  (total 78 MB)

  float* out_att    = (float*)d_out;
  float* out_mean   = out_att + 1048576;
  float* out_logits = out_att + 1114112;

  // ---- gate: is a 512-block cooperative launch of k_mega guaranteed co-resident? ----
  int dev = 0; (void)hipGetDevice(&dev);
  int coop = 0; (void)hipDeviceGetAttribute(&coop, hipDeviceAttributeCooperativeLaunch, dev);
  int ncu = 0;  (void)hipDeviceGetAttribute(&ncu, hipDeviceAttributeMultiprocessorCount, dev);
  int perCU = 0;
  hipError_t oe = hipOccupancyMaxActiveBlocksPerMultiprocessor(
                      &perCU, (const void*)k_mega, 256, (size_t)MEGA_DYN_LDS);
  bool use_coop = (coop != 0) && (oe == hipSuccess) && ((long)perCU * (long)ncu >= 512);

  if (use_coop){
    void* args[] = { (void*)&qv, (void*)&tokens, (void*)&gate,
                     (void*)&Wq, (void*)&bq, (void*)&Wk, (void*)&bk,
                     (void*)&Wv, (void*)&bv,
                     (void*)&qvB, (void*)&WqT, (void*)&WkB, (void*)&WvT,
                     (void*)&qf, (void*)&qb, (void*)&U, (void*)&ctxb,
                     (void*)&out_att, (void*)&out_mean, (void*)&out_logits };
    hipError_t le = hipLaunchCooperativeKernel((const void*)k_mega, dim3(512), dim3(256),
                                               args, MEGA_DYN_LDS, stream);
    if (le == hipSuccess) return;
    use_coop = false;                          // fall through to proven pipeline
  }

  (void)hipFuncSetAttribute((const void*)k_attn,
                            hipFuncAttributeMaxDynamicSharedMemorySize, K3_LDS);
  k_convert <<<dim3(256, 3),    256, 0,      stream>>>(Wq, Wk, Wv, WqT, WkB, WvT);
  k_qproj   <<<dim3(16, 16),    256, 0,      stream>>>(qv, WqT, bq, qf, qb);
  k_umat    <<<dim3(16, 16, 16),256, 0,      stream>>>(qb, WkB, U);
  k_attn    <<<dim3(1024),      256, K3_LDS, stream>>>(tokens, gate, U, qf, bk,
                                                       out_logits, out_mean, ctxb);
  k_attended<<<dim3(16, 16),    256, 0,      stream>>>(ctxb, WvT, bv, out_att);
}

// Round 3
// 177.328 us; speedup vs baseline: 1.0006x; 1.0006x over previous
//
#include <hip/hip_runtime.h>
#include <hip/hip_bf16.h>
#include <hip/hip_cooperative_groups.h>

namespace cg = cooperative_groups;

typedef __attribute__((ext_vector_type(4))) float f32x4;
typedef __attribute__((ext_vector_type(8))) short bf16x8;
typedef unsigned int u32;
typedef unsigned short u16;

#define DEV static __device__ __forceinline__

// T=32,B=32 -> TB=1024 ; N=64 ; D=1024 ; H=16 ; HD=64
// d_out: attended [1024x1024] f32 @0 ; mean_attn [1024x64] @1048576 ; logits [1024x16x64] @1114112

DEV u16 f2bf(float x){                       // RNE f32->bf16
  union { float f; u32 u; } v; v.f = x;
  u32 r = v.u + 0x7FFFu + ((v.u >> 16) & 1u);
  return (u16)(r >> 16);
}
DEV float bf2f(u16 s){
  union { u32 u; float f; } v; v.u = ((u32)s) << 16;
  return v.f;
}

#define MFMA16(a,b,c) __builtin_amdgcn_mfma_f32_16x16x32_bf16((a),(b),(c),0,0,0)

DEV int tok_off(int n, int dbyte){ return n*2048 + (dbyte ^ ((n & 7) << 4)); }

// f32 token-buffer swizzle: XOR inner-row byte offset (bits 4..6) by a row hash.
// Involution; 16B-granular so global_load_lds source stays 16B-aligned & coalesced.
#define SWZ(n) ((((n)&3)<<5) | ((((n)>>2)&1)<<4))

// lgkm-only block barrier: orders LDS, does NOT drain vmcnt (keeps global_load_lds
// staging in flight across it). Full syncthreads is used where staged data is consumed.
DEV void bar_lgkm(){
  __builtin_amdgcn_sched_barrier(0);
  asm volatile("s_waitcnt lgkmcnt(0)" ::: "memory");
  __builtin_amdgcn_s_barrier();
  __builtin_amdgcn_sched_barrier(0);
}

// 8x f32 -> bf16x8 via packed RNE converts
DEV bf16x8 cvt8(f32x4 lo, f32x4 hi){
  union { u32 u[4]; bf16x8 v; } r;
  asm("v_cvt_pk_bf16_f32 %0, %1, %2" : "=v"(r.u[0]) : "v"(lo.x), "v"(lo.y));
  asm("v_cvt_pk_bf16_f32 %0, %1, %2" : "=v"(r.u[1]) : "v"(lo.z), "v"(lo.w));
  asm("v_cvt_pk_bf16_f32 %0, %1, %2" : "=v"(r.u[2]) : "v"(hi.x), "v"(hi.y));
  asm("v_cvt_pk_bf16_f32 %0, %1, %2" : "=v"(r.u[3]) : "v"(hi.z), "v"(hi.w));
  return r.v;
}

// Stage 8 tokens (f32, 32KB) of (tbn, tk0..tk0+7) into buffer bb via async
// global_load_lds. Dest is linear (HW: wave-uniform base + lane*16); the bank
// swizzle is applied by pre-swizzling the per-lane GLOBAL source address.
DEV void stage8(const float* __restrict__ tokens, int tbn, int tk0,
                char* smem, int bb, int w, int l){
  char* ldsb = smem + (size_t)bb*32768 + (size_t)w*8192;
  const char* gb = (const char*)tokens + (size_t)tbn*262144 + (size_t)tk0*4096;
  #pragma unroll
  for (int j = 0; j < 8; ++j){
    const int nloc  = w*2 + (j >> 2);
    const int inner = (((j & 3)*1024) + l*16) ^ SWZ(nloc);
    __builtin_amdgcn_global_load_lds(
        (const __attribute__((address_space(1))) u32*)(gb + (size_t)nloc*4096 + inner),
        (__attribute__((address_space(3))) u32*)(ldsb + j*1024),
        16, 0, 0);
  }
}

// ============================ MEGA (cooperative) path ============================
// Dynamic LDS: 64KB = TWO 32KB f32 token buffers (8 tokens each, double-buffered).
// Scratch lives in a 10.25KB static overlay. 74.25KB/block -> 2/CU.
#define MEGA_DYN_LDS 65536

__global__ __launch_bounds__(256, 2) void k_mega(
    const float* __restrict__ qv, const float* __restrict__ tokens,
    const float* __restrict__ gate,
    const float* __restrict__ Wq, const float* __restrict__ bq,
    const float* __restrict__ Wk, const float* __restrict__ bk,
    const float* __restrict__ Wv, const float* __restrict__ bv,
    u16* __restrict__ qvB, u16* __restrict__ WqT, u16* __restrict__ WkB,
    u16* __restrict__ WvT, float* __restrict__ qf, u16* __restrict__ qb,
    u16* __restrict__ U, u16* __restrict__ ctxb,
    float* __restrict__ out_att, float* __restrict__ out_mean,
    float* __restrict__ out_logits){
  extern __shared__ __align__(16) char smem[];        // 2 x 32KB f32 token buffers
  __shared__ __align__(16) char sstat[10496];         // static scratch overlay
  cg::grid_group grid = cg::this_grid();
  const int tid = threadIdx.x;
  const int bx  = blockIdx.x;                 // 0..511
  const int l = tid & 63, w = tid >> 6, g = l >> 4, li = l & 15;

  // ================= P0: qv -> bf16 ; weights -> bf16 (WqT,WvT transposed; Wk plain) ======
  {
    const f32x4* s4 = (const f32x4*)qv;
    uint2* d2 = (uint2*)qvB;
    int g0 = bx*256 + tid;
    #pragma unroll
    for (int i = 0; i < 2; ++i){
      int idx = g0 + i*131072;
      f32x4 v = s4[idx];
      uint2 pk;
      pk.x = (u32)f2bf(v.x) | ((u32)f2bf(v.y) << 16);
      pk.y = (u32)f2bf(v.z) | ((u32)f2bf(v.w) << 16);
      d2[idx] = pk;
    }
  }
  {
    u16 (*tile)[65] = (u16 (*)[65])sstat;             // 8320B <= 10496
    for (int tl = bx; tl < 768; tl += 512){
      __syncthreads();
      const int which = tl >> 8, t8 = tl & 255;
      const float* src = which==0 ? Wq : (which==1 ? Wk : Wv);
      const int bi = (t8 >> 4) << 6, bj = (t8 & 15) << 6;
      #pragma unroll
      for (int k2 = 0; k2 < 16; ++k2){
        int e = tid + (k2 << 8); int r = e >> 6, c = e & 63;
        tile[r][c] = f2bf(src[(size_t)(bi + r)*1024 + bj + c]);
      }
      __syncthreads();
      if (which == 1){
        #pragma unroll
        for (int k2 = 0; k2 < 16; ++k2){
          int e = tid + (k2 << 8); int r = e >> 6, c = e & 63;
          WkB[(size_t)(bi + r)*1024 + bj + c] = tile[r][c];
        }
      } else {
        u16* dst = which==0 ? WqT : WvT;
        #pragma unroll
        for (int k2 = 0; k2 < 16; ++k2){
          int e = tid + (k2 << 8); int r = e >> 6, c = e & 63;
          dst[(size_t)(bj + r)*1024 + bi + c] = tile[c][r];
        }
      }
    }
  }
  __threadfence(); grid.sync(); __threadfence();

  // ================= P1: q = qvB @ WqT + bq ; 512 tiles 64x32 =============================
  {
    const int wm = w & 1, wn = w >> 1;
    const int m_base = (bx >> 5)*64 + wm*32;
    const int n_base = (bx & 31)*32 + wn*16;
    f32x4 acc[2]; acc[0] = (f32x4)0.0f; acc[1] = (f32x4)0.0f;
    #pragma unroll 4
    for (int kb = 0; kb < 32; ++kb){
      const int k0 = kb*32 + g*8;
      bf16x8 b = *(const bf16x8*)(WqT + (size_t)(n_base + li)*1024 + k0);
      #pragma unroll
      for (int rt = 0; rt < 2; ++rt){
        bf16x8 a = *(const bf16x8*)(qvB + (size_t)(m_base + rt*16 + li)*1024 + k0);
        acc[rt] = MFMA16(a, b, acc[rt]);
      }
    }
    #pragma unroll
    for (int rt = 0; rt < 2; ++rt)
      #pragma unroll
      for (int r = 0; r < 4; ++r){
        int m = m_base + rt*16 + g*4 + r;     // C/D map: row=(lane>>4)*4+reg, col=lane&15
        int n = n_base + li;
        float val = acc[rt][r] + bq[n];
        qf[(size_t)m*1024 + n] = val;
        qb[(size_t)m*1024 + n] = f2bf(val);
      }
  }
  __threadfence(); grid.sync(); __threadfence();

  // ================= P2: U[tb][h][d] = q[tb][hslice] . Wk[d][hslice] ; 8 tiles/block ======
  {
    u16 (*stile)[64] = (u16 (*)[64])sstat;            // 8192B
    const int wm = w & 1, wn = w >> 1;
    for (int i = 0; i < 8; ++i){
      const int tl = bx*8 + i;
      const int tb0 = (tl >> 8)*64, d0 = ((tl >> 4) & 15)*64, h = tl & 15;
      f32x4 acc[2][2];
      #pragma unroll
      for (int a0=0;a0<2;++a0)
        #pragma unroll
        for (int b0=0;b0<2;++b0) acc[a0][b0] = (f32x4)0.0f;
      #pragma unroll
      for (int kb = 0; kb < 2; ++kb){
        const int k0 = h*64 + kb*32 + g*8;
        bf16x8 a[2], b[2];
        #pragma unroll
        for (int rt=0;rt<2;++rt)
          a[rt] = *(const bf16x8*)(qb + (size_t)(tb0 + wm*32 + rt*16 + li)*1024 + k0);
        #pragma unroll
        for (int ct=0;ct<2;++ct)
          b[ct] = *(const bf16x8*)(WkB + (size_t)(d0 + wn*32 + ct*16 + li)*1024 + k0);
        #pragma unroll
        for (int rt=0;rt<2;++rt)
          #pragma unroll
          for (int ct=0;ct<2;++ct)
            acc[rt][ct] = MFMA16(a[rt], b[ct], acc[rt][ct]);
      }
      __syncthreads();
      #pragma unroll
      for (int rt=0;rt<2;++rt)
        #pragma unroll
        for (int ct=0;ct<2;++ct)
          #pragma unroll
          for (int r=0;r<4;++r)
            stile[wm*32 + rt*16 + g*4 + r][wn*32 + ct*16 + li] = f2bf(acc[rt][ct][r]);
      __syncthreads();
      const int rr = tid >> 2, cg4 = tid & 3;
      f32x4* dst = (f32x4*)(U + ((size_t)(tb0 + rr)*16 + h)*1024 + d0 + cg4*16);
      const f32x4* s4 = (const f32x4*)(&stile[rr][cg4*16]);
      dst[0] = s4[0]; dst[1] = s4[1];
    }
  }
  __threadfence(); grid.sync(); __threadfence();

  // ================= P3: fused attention, async global_load_lds double-buffer =============
  // 16 rounds = 2 tb x 8 chunks of 8 tokens (f32 in LDS). Stage for round r+1 issued
  // right after round r's top __syncthreads (the only point buf[(r+1)&1] is provably
  // free); drained by the NEXT top barrier -> in-flight window = one full round.
  // In-round barriers are lgkm-only so staging stays in flight across them.
  {
    float* part_s   = (float*)(sstat);          // [4][64][4] 4096B
    float* logits_s = (float*)(sstat + 4096);   // [16][64]   4096B
    float* p_s      = (float*)(sstat + 8192);   // [8][16]    512B
    float* csum     = (float*)(sstat + 10240);  // [16]
    float* r_s      = (float*)(sstat + 10304);  // [16]
    float* mzs      = (float*)(sstat + 10368);  // [16][2]
    const int sh = tid >> 4, sj = tid & 15;

    __syncthreads();                            // P2's stile readers done before overlay reuse
    stage8(tokens, bx, 0, smem, 0, w, l);       // prologue: chunk 0 -> buf0

    float m_run = -1e30f, z_run = 0.0f;
    f32x4 cacc[4][4];
    bf16x8 a[8];                                // per-tb A-fragments (round-invariant)

    for (int r = 0; r < 16; ++r){
      const int c = r & 7, n0 = c*8;
      const int tb = bx + (r >> 3)*512;
      char* bufc = smem + (size_t)(r & 1)*32768;

      __syncthreads();                          // (A) stage for r visible; buf[(r+1)&1] free
      if (r + 1 < 16)
        stage8(tokens, bx + ((r+1) >> 3)*512, ((r+1) & 7)*8, smem, (r+1) & 1, w, l);

      if (c == 0){
        m_run = -1e30f; z_run = 0.0f;
        #pragma unroll
        for (int i=0;i<4;++i)
          #pragma unroll
          for (int j=0;j<4;++j) cacc[i][j] = (f32x4)0.0f;
        const bf16x8* Ub = (const bf16x8*)(U + (size_t)tb*16384);
        #pragma unroll
        for (int i = 0; i < 8; ++i)
          a[i] = Ub[li*128 + (w*8 + i)*4 + g];
        // csum[h] = q[tb, h*64:] . bk[h*64:]  (visible to softmax after (B))
        const float* qp = qf + (size_t)tb*1024 + sh*64 + sj*4;
        const float* bp = bk + sh*64 + sj*4;
        float part = qp[0]*bp[0] + qp[1]*bp[1] + qp[2]*bp[2] + qp[3]*bp[3];
        part += __shfl_xor(part, 1); part += __shfl_xor(part, 2);
        part += __shfl_xor(part, 4); part += __shfl_xor(part, 8);
        if (sj == 0) csum[sh] = part;
      }

      // ---- QK^T: 8 tokens, K split 4 ways across waves; f32->bf16 at read ----
      {
        const int row = li & 7;                 // cols 8..15 duplicate rows (discarded)
        const int sw  = SWZ(row);
        f32x4 acc = (f32x4)0.0f;
        #pragma unroll
        for (int i = 0; i < 8; ++i){
          const int p0b = (w*8 + i)*128 + g*32;
          f32x4 lo = *(const f32x4*)(bufc + row*4096 + ((p0b     ) ^ sw));
          f32x4 hi = *(const f32x4*)(bufc + row*4096 + ((p0b + 16) ^ sw));
          acc = MFMA16(a[i], cvt8(lo, hi), acc);
        }
        *(f32x4*)(part_s + (size_t)(w*64 + l)*4) = acc;
      }
      bar_lgkm();                               // (B)

      // ---- softmax over the 8-token chunk; reads 4 wave-partials directly ----
      if (sj < 8){
        const int idx = ((sh >> 2)*16 + sj)*4 + (sh & 3);
        float lv = part_s[idx] + part_s[256 + idx] + part_s[512 + idx] + part_s[768 + idx];
        lv = (lv + csum[sh])*0.125f + gate[(size_t)tb*64 + n0 + sj];
        logits_s[sh*64 + n0 + sj] = lv;
        out_logits[(size_t)tb*1024 + sh*64 + n0 + sj] = lv;
        float cm = lv;
        cm = fmaxf(cm, __shfl_xor(cm, 1));
        cm = fmaxf(cm, __shfl_xor(cm, 2));
        cm = fmaxf(cm, __shfl_xor(cm, 4));
        float m_new = fmaxf(m_run, cm);
        float rsc = __expf(m_run - m_new);
        float p0 = __expf(lv - m_new);
        float zs = p0;
        zs += __shfl_xor(zs, 1); zs += __shfl_xor(zs, 2); zs += __shfl_xor(zs, 4);
        z_run = z_run * rsc + zs;
        m_run = m_new;
        p_s[sj*16 + sh] = p0;
        if (sj == 0){
          r_s[sh] = rsc;
          if (c == 7){ mzs[sh*2] = m_new; mzs[sh*2 + 1] = 1.0f / z_run; }
        }
      }
      bar_lgkm();                               // (D)

      // ---- PV: f32 tokens direct from LDS (no unpack), contiguous reads ----
      {
        float rr4[4];
        #pragma unroll
        for (int hh = 0; hh < 4; ++hh) rr4[hh] = r_s[w*4 + hh];
        #pragma unroll
        for (int dq = 0; dq < 4; ++dq)
          #pragma unroll
          for (int hh = 0; hh < 4; ++hh) cacc[dq][hh] *= rr4[hh];
        #pragma unroll
        for (int nl = 0; nl < 8; ++nl){
          const f32x4 p = *(const f32x4*)(p_s + nl*16 + w*4);
          const int swn = SWZ(nl);
          #pragma unroll
          for (int dq = 0; dq < 4; ++dq){
            const f32x4 t = *(const f32x4*)(bufc + (size_t)nl*4096 + ((dq*1024 + l*16) ^ swn));
            #pragma unroll
            for (int hh = 0; hh < 4; ++hh)
              cacc[dq][hh] += t * p[hh];
          }
        }
      }

      // ---- per-tb epilogue ----
      if (c == 7){
        if (tid < 64){
          float s = 0.0f;
          #pragma unroll
          for (int h = 0; h < 16; ++h)
            s += __expf(logits_s[h*64 + tid] - mzs[h*2]) * mzs[h*2 + 1];
          out_mean[(size_t)tb*64 + tid] = s * 0.0625f;
        }
        #pragma unroll
        for (int hh = 0; hh < 4; ++hh){
          const int h = w*4 + hh;
          const float zinv = mzs[h*2 + 1];
          #pragma unroll
          for (int dq = 0; dq < 4; ++dq){
            f32x4 v = cacc[dq][hh];
            uint2 pk;
            pk.x = (u32)f2bf(v.x * zinv) | ((u32)f2bf(v.y * zinv) << 16);
            pk.y = (u32)f2bf(v.z * zinv) | ((u32)f2bf(v.w * zinv) << 16);
            *(uint2*)(ctxb + ((size_t)tb*16 + h)*1024 + dq*256 + l*4) = pk;
          }
        }
      }
    }
  }
  __threadfence(); grid.sync(); __threadfence();

  // ================= P4: attended = ctx @ WvT + bv ; 512 tiles 32(m) x 64(h-cols) =========
  {
    const int wm = w & 1, wn = w >> 1;
    const int m_base = (bx >> 4)*32, h = bx & 15;
    f32x4 acc[2]; acc[0] = (f32x4)0.0f; acc[1] = (f32x4)0.0f;
    #pragma unroll 4
    for (int kb = 0; kb < 32; ++kb){
      const int k0 = kb*32 + g*8;
      bf16x8 a = *(const bf16x8*)(ctxb + ((size_t)(m_base + wm*16 + li)*16 + h)*1024 + k0);
      #pragma unroll
      for (int ct = 0; ct < 2; ++ct){
        bf16x8 b = *(const bf16x8*)(WvT + (size_t)(h*64 + wn*32 + ct*16 + li)*1024 + k0);
        acc[ct] = MFMA16(a, b, acc[ct]);
      }
    }
    #pragma unroll
    for (int ct = 0; ct < 2; ++ct)
      #pragma unroll
      for (int r = 0; r < 4; ++r){
        int m = m_base + wm*16 + g*4 + r;
        int dout = h*64 + wn*32 + ct*16 + li;
        out_att[(size_t)m*1024 + dout] = acc[ct][r] + bv[dout];
      }
  }
}

// ============================ Fallback path (round-2 proven kernels) ============================
__global__ __launch_bounds__(256) void k_convert(
    const float* __restrict__ Wq, const float* __restrict__ Wk, const float* __restrict__ Wv,
    u16* __restrict__ WqT, u16* __restrict__ WkB, u16* __restrict__ WvT){
  __shared__ u16 tile[64][65];
  const int which = blockIdx.y;
  const float* src = which==0 ? Wq : (which==1 ? Wk : Wv);
  const int bi = (blockIdx.x >> 4) << 6;
  const int bj = (blockIdx.x & 15) << 6;
  const int t  = threadIdx.x;
  #pragma unroll
  for (int k2 = 0; k2 < 16; ++k2){
    int e = t + (k2 << 8);
    int r = e >> 6, c = e & 63;
    tile[r][c] = f2bf(src[(size_t)(bi + r)*1024 + bj + c]);
  }
  __syncthreads();
  if (which == 1){
    #pragma unroll
    for (int k2 = 0; k2 < 16; ++k2){
      int e = t + (k2 << 8); int r = e >> 6, c = e & 63;
      WkB[(size_t)(bi + r)*1024 + bj + c] = tile[r][c];
    }
  } else {
    u16* dst = which==0 ? WqT : WvT;
    #pragma unroll
    for (int k2 = 0; k2 < 16; ++k2){
      int e = t + (k2 << 8); int r = e >> 6, c = e & 63;
      dst[(size_t)(bj + r)*1024 + bi + c] = tile[c][r];
    }
  }
}

__global__ __launch_bounds__(256) void k_qproj(
    const float* __restrict__ qv, const u16* __restrict__ WqT, const float* __restrict__ bq,
    float* __restrict__ qf, u16* __restrict__ qb){
  const int l = threadIdx.x & 63, w = threadIdx.x >> 6;
  const int wm = w & 1, wn = w >> 1;
  const int g = l >> 4, li = l & 15;
  const int m_base = blockIdx.x*64 + wm*32;
  const int n_base = blockIdx.y*64 + wn*32;
  f32x4 acc[2][2];
  #pragma unroll
  for (int i=0;i<2;++i)
    #pragma unroll
    for (int j=0;j<2;++j) acc[i][j] = (f32x4)0.0f;

  #pragma unroll 4
  for (int kb = 0; kb < 32; ++kb){
    const int k0 = kb*32 + g*8;
    bf16x8 a[2], b[2];
    #pragma unroll
    for (int rt = 0; rt < 2; ++rt){
      const float* p = qv + (size_t)(m_base + rt*16 + li)*1024 + k0;
      f32x4 lo = *(const f32x4*)p;
      f32x4 hi = *(const f32x4*)(p+4);
      union { u16 s[8]; bf16x8 v; } u;
      u.s[0]=f2bf(lo.x); u.s[1]=f2bf(lo.y); u.s[2]=f2bf(lo.z); u.s[3]=f2bf(lo.w);
      u.s[4]=f2bf(hi.x); u.s[5]=f2bf(hi.y); u.s[6]=f2bf(hi.z); u.s[7]=f2bf(hi.w);
      a[rt] = u.v;
    }
    #pragma unroll
    for (int ct = 0; ct < 2; ++ct)
      b[ct] = *(const bf16x8*)(WqT + (size_t)(n_base + ct*16 + li)*1024 + k0);
    #pragma unroll
    for (int rt = 0; rt < 2; ++rt)
      #pragma unroll
      for (int ct = 0; ct < 2; ++ct)
        acc[rt][ct] = MFMA16(a[rt], b[ct], acc[rt][ct]);
  }
  #pragma unroll
  for (int rt=0;rt<2;++rt)
    #pragma unroll
    for (int ct=0;ct<2;++ct)
      #pragma unroll
      for (int r=0;r<4;++r){
        int m = m_base + rt*16 + g*4 + r;
        int n = n_base + ct*16 + li;
        float val = acc[rt][ct][r] + bq[n];
        qf[(size_t)m*1024 + n] = val;
        qb[(size_t)m*1024 + n] = f2bf(val);
      }
}

__global__ __launch_bounds__(256) void k_umat(
    const u16* __restrict__ qb, const u16* __restrict__ WkB, u16* __restrict__ U){
  __shared__ __align__(16) u16 stile[64][64];
  const int l = threadIdx.x & 63, w = threadIdx.x >> 6;
  const int wm = w & 1, wn = w >> 1, g = l >> 4, li = l & 15;
  const int tb0 = blockIdx.x*64, d0 = blockIdx.y*64, h = blockIdx.z;
  f32x4 acc[2][2];
  #pragma unroll
  for (int i=0;i<2;++i)
    #pragma unroll
    for (int j=0;j<2;++j) acc[i][j] = (f32x4)0.0f;

  #pragma unroll
  for (int kb = 0; kb < 2; ++kb){
    const int k0 = h*64 + kb*32 + g*8;
    bf16x8 a[2], b[2];
    #pragma unroll
    for (int rt=0;rt<2;++rt)
      a[rt] = *(const bf16x8*)(qb + (size_t)(tb0 + wm*32 + rt*16 + li)*1024 + k0);
    #pragma unroll
    for (int ct=0;ct<2;++ct)
      b[ct] = *(const bf16x8*)(WkB + (size_t)(d0 + wn*32 + ct*16 + li)*1024 + k0);
    #pragma unroll
    for (int rt=0;rt<2;++rt)
      #pragma unroll
      for (int ct=0;ct<2;++ct)
        acc[rt][ct] = MFMA16(a[rt], b[ct], acc[rt][ct]);
  }
  #pragma unroll
  for (int rt=0;rt<2;++rt)
    #pragma unroll
    for (int ct=0;ct<2;++ct)
      #pragma unroll
      for (int r=0;r<4;++r)
        stile[wm*32 + rt*16 + g*4 + r][wn*32 + ct*16 + li] = f2bf(acc[rt][ct][r]);
  __syncthreads();
  const int r = threadIdx.x >> 2, cg4 = threadIdx.x & 3;
  f32x4* dst = (f32x4*)(U + ((size_t)(tb0 + r)*16 + h)*1024 + d0 + cg4*16);
  const f32x4* s4 = (const f32x4*)(&stile[r][cg4*16]);
  dst[0] = s4[0]; dst[1] = s4[1];
}

#define K3_LDS 76032
__global__ __launch_bounds__(256, 2) void k_attn(
    const float* __restrict__ tokens, const float* __restrict__ gate,
    const u16* __restrict__ U, const float* __restrict__ qf, const float* __restrict__ bk,
    float* __restrict__ out_logits, float* __restrict__ out_mean, u16* __restrict__ ctx){
  extern __shared__ __align__(16) char smem[];
  float* part_s   = (float*)(smem + 65536);
  float* logits_s = (float*)(smem + 69632);
  float* p_s      = (float*)(smem + 73728);
  float* csum     = (float*)(smem + 75776);
  float* r_s      = (float*)(smem + 75840);
  float* mzs      = (float*)(smem + 75904);
  const int tb = blockIdx.x;
  const int tid = threadIdx.x;
  const int l = tid & 63, w = tid >> 6, g = l >> 4, li = l & 15;
  const int nt = w & 1, kh = w >> 1;
  const int sh = tid >> 4, sj = tid & 15;

  bf16x8 a[16];
  const bf16x8* Ub = (const bf16x8*)(U + (size_t)tb*16384);
  #pragma unroll
  for (int i = 0; i < 16; ++i)
    a[i] = Ub[li*128 + (kh*16 + i)*4 + g];

  {
    const float* qp = qf + (size_t)tb*1024 + sh*64 + sj*4;
    const float* bp = bk + sh*64 + sj*4;
    float part = qp[0]*bp[0] + qp[1]*bp[1] + qp[2]*bp[2] + qp[3]*bp[3];
    part += __shfl_xor(part, 1); part += __shfl_xor(part, 2);
    part += __shfl_xor(part, 4); part += __shfl_xor(part, 8);
    if (sj == 0) csum[sh] = part;
  }

  float m_run = -1e30f, z_run = 0.0f;
  f32x4 cacc[4][4];
  #pragma unroll
  for (int i=0;i<4;++i)
    #pragma unroll
    for (int j=0;j<4;++j) cacc[i][j] = (f32x4)0.0f;

  const f32x4* src4 = (const f32x4*)(tokens + (size_t)tb*65536);

  for (int c = 0; c < 2; ++c){
    const int n0 = c*32;
    __syncthreads();
    #pragma unroll 8
    for (int it = 0; it < 32; ++it){
      f32x4 v = src4[(size_t)(n0 + it)*256 + tid];
      uint2 pk;
      pk.x = (u32)f2bf(v.x) | ((u32)f2bf(v.y) << 16);
      pk.y = (u32)f2bf(v.z) | ((u32)f2bf(v.w) << 16);
      *(uint2*)(smem + tok_off(it, tid*8)) = pk;
    }
    __syncthreads();
    {
      f32x4 acc = (f32x4)0.0f;
      #pragma unroll
      for (int i = 0; i < 16; ++i){
        int kb = kh*16 + i;
        bf16x8 b = *(const bf16x8*)(smem + tok_off(nt*16 + li, (kb*32 + g*8)*2));
        acc = MFMA16(a[i], b, acc);
      }
      *(f32x4*)(part_s + (size_t)(w*64 + l)*4) = acc;
      __syncthreads();
      if (kh == 0){
        acc += *(const f32x4*)(part_s + (size_t)((w+2)*64 + l)*4);
        float gv = gate[(size_t)tb*64 + n0 + nt*16 + li];
        #pragma unroll
        for (int r = 0; r < 4; ++r){
          int h = g*4 + r;
          logits_s[h*64 + n0 + nt*16 + li] = (acc[r] + csum[h])*0.125f + gv;
        }
      }
      __syncthreads();
    }
    {
      float lv0 = logits_s[sh*64 + n0 + sj];
      float lv1 = logits_s[sh*64 + n0 + 16 + sj];
      out_logits[(size_t)tb*1024 + sh*64 + n0 + sj]      = lv0;
      out_logits[(size_t)tb*1024 + sh*64 + n0 + 16 + sj] = lv1;
      float cm = fmaxf(lv0, lv1);
      cm = fmaxf(cm, __shfl_xor(cm, 1)); cm = fmaxf(cm, __shfl_xor(cm, 2));
      cm = fmaxf(cm, __shfl_xor(cm, 4)); cm = fmaxf(cm, __shfl_xor(cm, 8));
      float m_new = fmaxf(m_run, cm);
      float rsc = __expf(m_run - m_new);
      float p0 = __expf(lv0 - m_new), p1 = __expf(lv1 - m_new);
      float zs = p0 + p1;
      zs += __shfl_xor(zs, 1); zs += __shfl_xor(zs, 2);
      zs += __shfl_xor(zs, 4); zs += __shfl_xor(zs, 8);
      z_run = z_run * rsc + zs;
      m_run = m_new;
      p_s[sj*16 + sh]        = p0;
      p_s[(sj + 16)*16 + sh] = p1;
      if (sj == 0){
        r_s[sh] = rsc;
        if (c == 1){ mzs[sh*2] = m_new; mzs[sh*2 + 1] = 1.0f / z_run; }
      }
    }
    __syncthreads();
    {
      float rr[4];
      #pragma unroll
      for (int hh = 0; hh < 4; ++hh) rr[hh] = r_s[w*4 + hh];
      #pragma unroll
      for (int dq = 0; dq < 4; ++dq)
        #pragma unroll
        for (int hh = 0; hh < 4; ++hh) cacc[dq][hh] *= rr[hh];
      for (int nl = 0; nl < 32; ++nl){
        f32x4 p = *(const f32x4*)(p_s + nl*16 + w*4);
        #pragma unroll
        for (int dq = 0; dq < 4; ++dq){
          uint2 t2 = *(const uint2*)(smem + tok_off(nl, (dq*256 + l*4)*2));
          float f0 = bf2f((u16)(t2.x & 0xFFFFu));
          float f1 = bf2f((u16)(t2.x >> 16));
          float f2 = bf2f((u16)(t2.y & 0xFFFFu));
          float f3 = bf2f((u16)(t2.y >> 16));
          #pragma unroll
          for (int hh = 0; hh < 4; ++hh){
            float av = p[hh];
            cacc[dq][hh].x += av*f0; cacc[dq][hh].y += av*f1;
            cacc[dq][hh].z += av*f2; cacc[dq][hh].w += av*f3;
          }
        }
      }
    }
  }

  if (tid < 64){
    float s = 0.0f;
    #pragma unroll
    for (int h = 0; h < 16; ++h)
      s += __expf(logits_s[h*64 + tid] - mzs[h*2]) * mzs[h*2 + 1];
    out_mean[(size_t)tb*64 + tid] = s * 0.0625f;
  }

  #pragma unroll
  for (int hh = 0; hh < 4; ++hh){
    const int h = w*4 + hh;
    const float zinv = mzs[h*2 + 1];
    #pragma unroll
    for (int dq = 0; dq < 4; ++dq){
      f32x4 v = cacc[dq][hh];
      uint2 pk;
      pk.x = (u32)f2bf(v.x * zinv) | ((u32)f2bf(v.y * zinv) << 16);
      pk.y = (u32)f2bf(v.z * zinv) | ((u32)f2bf(v.w * zinv) << 16);
      *(uint2*)(ctx + ((size_t)tb*16 + h)*1024 + dq*256 + l*4) = pk;
    }
  }
}

__global__ __launch_bounds__(256) void k_attended(
    const u16* __restrict__ ctx, const u16* __restrict__ WvT, const float* __restrict__ bv,
    float* __restrict__ out_att){
  const int l = threadIdx.x & 63, w = threadIdx.x >> 6;
  const int wm = w & 1, wn = w >> 1, g = l >> 4, li = l & 15;
  const int tb0 = blockIdx.x*64, h = blockIdx.y;
  f32x4 acc[2][2];
  #pragma unroll
  for (int i=0;i<2;++i)
    #pragma unroll
    for (int j=0;j<2;++j) acc[i][j] = (f32x4)0.0f;

  #pragma unroll 4
  for (int kb = 0; kb < 32; ++kb){
    const int k0 = kb*32 + g*8;
    bf16x8 a[2], b[2];
    #pragma unroll
    for (int rt=0;rt<2;++rt)
      a[rt] = *(const bf16x8*)(ctx + ((size_t)(tb0 + wm*32 + rt*16 + li)*16 + h)*1024 + k0);
    #pragma unroll
    for (int ct=0;ct<2;++ct)
      b[ct] = *(const bf16x8*)(WvT + (size_t)(h*64 + wn*32 + ct*16 + li)*1024 + k0);
    #pragma unroll
    for (int rt=0;rt<2;++rt)
      #pragma unroll
      for (int ct=0;ct<2;++ct)
        acc[rt][ct] = MFMA16(a[rt], b[ct], acc[rt][ct]);
  }
  #pragma unroll
  for (int rt=0;rt<2;++rt)
    #pragma unroll
    for (int ct=0;ct<2;++ct)
      #pragma unroll
      for (int r=0;r<4;++r){
        int m = tb0 + wm*32 + rt*16 + g*4 + r;
        int dout = h*64 + wn*32 + ct*16 + li;
        out_att[(size_t)m*1024 + dout] = acc[rt][ct][r] + bv[dout];
      }
}

// ---------------- launch ----------------
extern "C" void kernel_launch(void* const* d_in, const int* in_sizes, int n_in,
                              void* d_out, int out_size, void* d_ws, size_t ws_size,
                              hipStream_t stream){
  const float* qv     = (const float*)d_in[0];
  const float* tokens = (const float*)d_in[1];
  const float* gate   = (const float*)d_in[2];
  const float* Wq     = (const float*)d_in[3];
  const float* bq     = (const float*)d_in[4];
  const float* Wk     = (const float*)d_in[5];
  const float* bk     = (const float*)d_in[6];
  const float* Wv     = (const float*)d_in[7];
  const float* bv     = (const float*)d_in[8];

  char* ws = (char*)d_ws;
  u16*   qvB = (u16*)(ws);                       // 2 MB
  u16*   WqT = (u16*)(ws + (2u<<20));            // 2 MB
  u16*   WkB = (u16*)(ws + (4u<<20));            // 2 MB
  u16*   WvT = (u16*)(ws + (6u<<20));            // 2 MB
  float* qf  = (float*)(ws + (8u<<20));          // 4 MB
  u16*   qb  = (u16*)(ws + (12u<<20));           // 2 MB
  u16*   U   = (u16*)(ws + (14u<<20));           // 32 MB
  u16*   ctxb= (u16*)(ws + (46u<<20));           // 32 MB  (total 78 MB)

  float* out_att    = (float*)d_out;
  float* out_mean   = out_att + 1048576;
  float* out_logits = out_att + 1114112;

  // ---- gate: is a 512-block cooperative launch of k_mega guaranteed co-resident? ----
  int dev = 0; (void)hipGetDevice(&dev);
  int coop = 0; (void)hipDeviceGetAttribute(&coop, hipDeviceAttributeCooperativeLaunch, dev);
  int ncu = 0;  (void)hipDeviceGetAttribute(&ncu, hipDeviceAttributeMultiprocessorCount, dev);
  int perCU = 0;
  hipError_t oe = hipOccupancyMaxActiveBlocksPerMultiprocessor(
                      &perCU, (const void*)k_mega, 256, (size_t)MEGA_DYN_LDS);
  bool use_coop = (coop != 0) && (oe == hipSuccess) && ((long)perCU * (long)ncu >= 512);

  if (use_coop){
    void* args[] = { (void*)&qv, (void*)&tokens, (void*)&gate,
                     (void*)&Wq, (void*)&bq, (void*)&Wk, (void*)&bk,
                     (void*)&Wv, (void*)&bv,
                     (void*)&qvB, (void*)&WqT, (void*)&WkB, (void*)&WvT,
                     (void*)&qf, (void*)&qb, (void*)&U, (void*)&ctxb,
                     (void*)&out_att, (void*)&out_mean, (void*)&out_logits };
    hipError_t le = hipLaunchCooperativeKernel((const void*)k_mega, dim3(512), dim3(256),
                                               args, MEGA_DYN_LDS, stream);
    if (le == hipSuccess) return;
    use_coop = false;                          // fall through to proven pipeline
  }

  (void)hipFuncSetAttribute((const void*)k_attn,
                            hipFuncAttributeMaxDynamicSharedMemorySize, K3_LDS);
  k_convert <<<dim3(256, 3),    256, 0,      stream>>>(Wq, Wk, Wv, WqT, WkB, WvT);
  k_qproj   <<<dim3(16, 16),    256, 0,      stream>>>(qv, WqT, bq, qf, qb);
  k_umat    <<<dim3(16, 16, 16),256, 0,      stream>>>(qb, WkB, U);
  k_attn    <<<dim3(1024),      256, K3_LDS, stream>>>(tokens, gate, U, qf, bk,
                                                       out_logits, out_mean, ctxb);
  k_attended<<<dim3(16, 16),    256, 0,      stream>>>(ctxb, WvT, bv, out_att);
}

// Round 4
// 160.167 us; speedup vs baseline: 1.1078x; 1.1071x over previous
//
#include <hip/hip_runtime.h>
#include <hip/hip_bf16.h>

typedef __attribute__((ext_vector_type(4))) float f32x4;
typedef __attribute__((ext_vector_type(8))) short bf16x8;
typedef unsigned int u32;
typedef unsigned short u16;

#define DEV static __device__ __forceinline__

// T=32,B=32 -> TB=1024 ; N=64 ; D=1024 ; H=16 ; HD=64
// d_out: attended [1024x1024] f32 @0 ; mean_attn [1024x64] @1048576 ; logits [1024x16x64] @1114112

DEV u16 f2bf(float x){                       // RNE f32->bf16
  union { float f; u32 u; } v; v.f = x;
  u32 r = v.u + 0x7FFFu + ((v.u >> 16) & 1u);
  return (u16)(r >> 16);
}
DEV float bf2f(u16 s){
  union { u32 u; float f; } v; v.u = ((u32)s) << 16;
  return v.f;
}

#define MFMA16(a,b,c) __builtin_amdgcn_mfma_f32_16x16x32_bf16((a),(b),(c),0,0,0)

// f32 token-buffer swizzle: XOR inner-row byte offset (bits 4..6) by a token hash.
// Involution; 16B-granular so global_load_lds source stays 16B-aligned & coalesced.
#define SWZ(n) ((((n)&3)<<5) | ((((n)>>2)&1)<<4))

// lgkm-only block barrier: orders LDS, does NOT drain vmcnt (keeps global_load_lds
// staging in flight across it).
DEV void bar_lgkm(){
  __builtin_amdgcn_sched_barrier(0);
  asm volatile("s_waitcnt lgkmcnt(0)" ::: "memory");
  __builtin_amdgcn_s_barrier();
  __builtin_amdgcn_sched_barrier(0);
}
// full barrier: drains staging (vmcnt) + LDS, then barrier.
DEV void bar_full(){
  __builtin_amdgcn_sched_barrier(0);
  asm volatile("s_waitcnt vmcnt(0) lgkmcnt(0)" ::: "memory");
  __builtin_amdgcn_s_barrier();
  __builtin_amdgcn_sched_barrier(0);
}

// 8x f32 -> bf16x8 via packed RNE converts
DEV bf16x8 cvt8(f32x4 lo, f32x4 hi){
  union { u32 u[4]; bf16x8 v; } r;
  asm("v_cvt_pk_bf16_f32 %0, %1, %2" : "=v"(r.u[0]) : "v"(lo.x), "v"(lo.y));
  asm("v_cvt_pk_bf16_f32 %0, %1, %2" : "=v"(r.u[1]) : "v"(lo.z), "v"(lo.w));
  asm("v_cvt_pk_bf16_f32 %0, %1, %2" : "=v"(r.u[2]) : "v"(hi.x), "v"(hi.y));
  asm("v_cvt_pk_bf16_f32 %0, %1, %2" : "=v"(r.u[3]) : "v"(hi.z), "v"(hi.w));
  return r.v;
}

// Stage 8 tokens (f32, 32KB) of (tbn, tk0..tk0+7) into buffer bb via async
// global_load_lds. LDS dest is linear (HW: wave-uniform base + lane*16); the bank
// swizzle is applied by pre-swizzling the per-lane GLOBAL source address.
DEV void stage8(const float* __restrict__ tokens, int tbn, int tk0,
                char* smem, int bb, int w, int l){
  char* ldsb = smem + (size_t)bb*32768 + (size_t)w*8192;
  const char* gb = (const char*)tokens + (size_t)tbn*262144 + (size_t)tk0*4096;
  #pragma unroll
  for (int j = 0; j < 8; ++j){
    const int nloc  = w*2 + (j >> 2);
    const int inner = (((j & 3)*1024) + l*16) ^ SWZ(nloc);
    __builtin_amdgcn_global_load_lds(
        (const __attribute__((address_space(1))) u32*)(gb + (size_t)nloc*4096 + inner),
        (__attribute__((address_space(3))) u32*)(ldsb + j*1024),
        16, 0, 0);
  }
}

// ============================ 5-kernel pipeline (the timed path) ============================
__global__ __launch_bounds__(256) void k_convert(
    const float* __restrict__ Wq, const float* __restrict__ Wk, const float* __restrict__ Wv,
    u16* __restrict__ WqT, u16* __restrict__ WkB, u16* __restrict__ WvT){
  __shared__ u16 tile[64][65];
  const int which = blockIdx.y;
  const float* src = which==0 ? Wq : (which==1 ? Wk : Wv);
  const int bi = (blockIdx.x >> 4) << 6;
  const int bj = (blockIdx.x & 15) << 6;
  const int t  = threadIdx.x;
  #pragma unroll
  for (int k2 = 0; k2 < 16; ++k2){
    int e = t + (k2 << 8);
    int r = e >> 6, c = e & 63;
    tile[r][c] = f2bf(src[(size_t)(bi + r)*1024 + bj + c]);
  }
  __syncthreads();
  if (which == 1){
    #pragma unroll
    for (int k2 = 0; k2 < 16; ++k2){
      int e = t + (k2 << 8); int r = e >> 6, c = e & 63;
      WkB[(size_t)(bi + r)*1024 + bj + c] = tile[r][c];
    }
  } else {
    u16* dst = which==0 ? WqT : WvT;
    #pragma unroll
    for (int k2 = 0; k2 < 16; ++k2){
      int e = t + (k2 << 8); int r = e >> 6, c = e & 63;
      dst[(size_t)(bj + r)*1024 + bi + c] = tile[c][r];
    }
  }
}

__global__ __launch_bounds__(256) void k_qproj(
    const float* __restrict__ qv, const u16* __restrict__ WqT, const float* __restrict__ bq,
    float* __restrict__ qf, u16* __restrict__ qb){
  const int l = threadIdx.x & 63, w = threadIdx.x >> 6;
  const int wm = w & 1, wn = w >> 1;
  const int g = l >> 4, li = l & 15;
  const int m_base = blockIdx.x*64 + wm*32;
  const int n_base = blockIdx.y*64 + wn*32;
  f32x4 acc[2][2];
  #pragma unroll
  for (int i=0;i<2;++i)
    #pragma unroll
    for (int j=0;j<2;++j) acc[i][j] = (f32x4)0.0f;

  #pragma unroll 4
  for (int kb = 0; kb < 32; ++kb){
    const int k0 = kb*32 + g*8;
    bf16x8 a[2], b[2];
    #pragma unroll
    for (int rt = 0; rt < 2; ++rt){
      const float* p = qv + (size_t)(m_base + rt*16 + li)*1024 + k0;
      f32x4 lo = *(const f32x4*)p;
      f32x4 hi = *(const f32x4*)(p+4);
      union { u16 s[8]; bf16x8 v; } u;
      u.s[0]=f2bf(lo.x); u.s[1]=f2bf(lo.y); u.s[2]=f2bf(lo.z); u.s[3]=f2bf(lo.w);
      u.s[4]=f2bf(hi.x); u.s[5]=f2bf(hi.y); u.s[6]=f2bf(hi.z); u.s[7]=f2bf(hi.w);
      a[rt] = u.v;
    }
    #pragma unroll
    for (int ct = 0; ct < 2; ++ct)
      b[ct] = *(const bf16x8*)(WqT + (size_t)(n_base + ct*16 + li)*1024 + k0);
    #pragma unroll
    for (int rt = 0; rt < 2; ++rt)
      #pragma unroll
      for (int ct = 0; ct < 2; ++ct)
        acc[rt][ct] = MFMA16(a[rt], b[ct], acc[rt][ct]);
  }
  #pragma unroll
  for (int rt=0;rt<2;++rt)
    #pragma unroll
    for (int ct=0;ct<2;++ct)
      #pragma unroll
      for (int r=0;r<4;++r){
        int m = m_base + rt*16 + g*4 + r;   // C/D map: row=(lane>>4)*4+reg, col=lane&15
        int n = n_base + ct*16 + li;
        float val = acc[rt][ct][r] + bq[n];
        qf[(size_t)m*1024 + n] = val;
        qb[(size_t)m*1024 + n] = f2bf(val);
      }
}

__global__ __launch_bounds__(256) void k_umat(
    const u16* __restrict__ qb, const u16* __restrict__ WkB, u16* __restrict__ U){
  __shared__ __align__(16) u16 stile[64][64];
  const int l = threadIdx.x & 63, w = threadIdx.x >> 6;
  const int wm = w & 1, wn = w >> 1, g = l >> 4, li = l & 15;
  const int tb0 = blockIdx.x*64, d0 = blockIdx.y*64, h = blockIdx.z;
  f32x4 acc[2][2];
  #pragma unroll
  for (int i=0;i<2;++i)
    #pragma unroll
    for (int j=0;j<2;++j) acc[i][j] = (f32x4)0.0f;

  #pragma unroll
  for (int kb = 0; kb < 2; ++kb){
    const int k0 = h*64 + kb*32 + g*8;
    bf16x8 a[2], b[2];
    #pragma unroll
    for (int rt=0;rt<2;++rt)
      a[rt] = *(const bf16x8*)(qb + (size_t)(tb0 + wm*32 + rt*16 + li)*1024 + k0);
    #pragma unroll
    for (int ct=0;ct<2;++ct)
      b[ct] = *(const bf16x8*)(WkB + (size_t)(d0 + wn*32 + ct*16 + li)*1024 + k0);
    #pragma unroll
    for (int rt=0;rt<2;++rt)
      #pragma unroll
      for (int ct=0;ct<2;++ct)
        acc[rt][ct] = MFMA16(a[rt], b[ct], acc[rt][ct]);
  }
  #pragma unroll
  for (int rt=0;rt<2;++rt)
    #pragma unroll
    for (int ct=0;ct<2;++ct)
      #pragma unroll
      for (int r=0;r<4;++r)
        stile[wm*32 + rt*16 + g*4 + r][wn*32 + ct*16 + li] = f2bf(acc[rt][ct][r]);
  __syncthreads();
  const int r = threadIdx.x >> 2, cg4 = threadIdx.x & 3;
  f32x4* dst = (f32x4*)(U + ((size_t)(tb0 + r)*16 + h)*1024 + d0 + cg4*16);
  const f32x4* s4 = (const f32x4*)(&stile[r][cg4*16]);
  dst[0] = s4[0]; dst[1] = s4[1];
}

// ---- k_attn: async global_load_lds double-buffered token stream (f32 in LDS) ----
// 8 rounds x 8 tokens per block (1 tb). Stage for round r+1 issued right after round
// r's top bar_full (the only point buf[(r+1)&1] is provably free); drained by the
// NEXT top bar_full -> in-flight window = one full round of compute.
// In-round barriers are lgkm-only so staging stays in flight across them.
// LDS: 64KB dyn (2x32KB buffers) + 8.75KB static -> 2 blocks/CU.
#define K3_LDS 65536
__global__ __launch_bounds__(256, 2) void k_attn(
    const float* __restrict__ tokens, const float* __restrict__ gate,
    const u16* __restrict__ U, const float* __restrict__ qf, const float* __restrict__ bk,
    float* __restrict__ out_logits, float* __restrict__ out_mean, u16* __restrict__ ctx){
  extern __shared__ __align__(16) char smem[];
  __shared__ __align__(16) char sstat[8960];
  float* part_s   = (float*)(sstat);          // [4][64][4] 4096B
  float* logits_s = (float*)(sstat + 4096);   // [16][64]   4096B
  float* p_s      = (float*)(sstat + 8192);   // [8][16]    512B
  float* csum     = (float*)(sstat + 8704);   // [16]
  float* r_s      = (float*)(sstat + 8768);   // [16]
  float* mzs      = (float*)(sstat + 8832);   // [16][2]
  const int tb = blockIdx.x;
  const int tid = threadIdx.x;
  const int l = tid & 63, w = tid >> 6, g = l >> 4, li = l & 15;
  const int sh = tid >> 4, sj = tid & 15;

  // per-tb A-fragments: U[tb][h=li][D-slice of wave w]
  bf16x8 a[8];
  const bf16x8* Ub = (const bf16x8*)(U + (size_t)tb*16384);
  #pragma unroll
  for (int i = 0; i < 8; ++i)
    a[i] = Ub[li*128 + (w*8 + i)*4 + g];

  // csum[h] = q[tb, h*64:] . bk[h*64:]
  {
    const float* qp = qf + (size_t)tb*1024 + sh*64 + sj*4;
    const float* bp = bk + sh*64 + sj*4;
    float part = qp[0]*bp[0] + qp[1]*bp[1] + qp[2]*bp[2] + qp[3]*bp[3];
    part += __shfl_xor(part, 1); part += __shfl_xor(part, 2);
    part += __shfl_xor(part, 4); part += __shfl_xor(part, 8);
    if (sj == 0) csum[sh] = part;
  }

  float m_run = -1e30f, z_run = 0.0f;
  f32x4 cacc[4][4];
  #pragma unroll
  for (int i=0;i<4;++i)
    #pragma unroll
    for (int j=0;j<4;++j) cacc[i][j] = (f32x4)0.0f;

  stage8(tokens, tb, 0, smem, 0, w, l);       // prologue: chunk 0 -> buf0

  for (int r = 0; r < 8; ++r){
    const int n0 = r*8;
    char* bufc = smem + (size_t)(r & 1)*32768;

    bar_full();                               // (A) stage for r landed; buf[(r+1)&1] free
    if (r + 1 < 8)
      stage8(tokens, tb, (r+1)*8, smem, (r+1) & 1, w, l);

    // ---- QK^T: 8 tokens, K split 4 ways across waves; f32->bf16 at read ----
    {
      const int row = li & 7;                 // cols 8..15 duplicate rows (discarded)
      const int sw  = SWZ(row);
      f32x4 acc = (f32x4)0.0f;
      #pragma unroll
      for (int i = 0; i < 8; ++i){
        const int p0b = (w*8 + i)*128 + g*32;
        f32x4 lo = *(const f32x4*)(bufc + row*4096 + ((p0b     ) ^ sw));
        f32x4 hi = *(const f32x4*)(bufc + row*4096 + ((p0b + 16) ^ sw));
        acc = MFMA16(a[i], cvt8(lo, hi), acc);
      }
      *(f32x4*)(part_s + (size_t)(w*64 + l)*4) = acc;
    }
    bar_lgkm();                               // (B)

    // ---- online softmax over the 8-token chunk; reads 4 wave-partials ----
    if (sj < 8){
      const int idx = ((sh >> 2)*16 + sj)*4 + (sh & 3);
      float lv = part_s[idx] + part_s[256 + idx] + part_s[512 + idx] + part_s[768 + idx];
      lv = (lv + csum[sh])*0.125f + gate[(size_t)tb*64 + n0 + sj];
      logits_s[sh*64 + n0 + sj] = lv;
      out_logits[(size_t)tb*1024 + sh*64 + n0 + sj] = lv;
      float cm = lv;
      cm = fmaxf(cm, __shfl_xor(cm, 1));
      cm = fmaxf(cm, __shfl_xor(cm, 2));
      cm = fmaxf(cm, __shfl_xor(cm, 4));
      float m_new = fmaxf(m_run, cm);
      float rsc = __expf(m_run - m_new);
      float p0 = __expf(lv - m_new);
      float zs = p0;
      zs += __shfl_xor(zs, 1); zs += __shfl_xor(zs, 2); zs += __shfl_xor(zs, 4);
      z_run = z_run * rsc + zs;
      m_run = m_new;
      p_s[sj*16 + sh] = p0;
      if (sj == 0){
        r_s[sh] = rsc;
        if (r == 7){ mzs[sh*2] = m_new; mzs[sh*2 + 1] = 1.0f / z_run; }
      }
    }
    bar_lgkm();                               // (D)

    // ---- PV: f32 tokens direct from LDS (no unpack), contiguous reads ----
    {
      float rr4[4];
      #pragma unroll
      for (int hh = 0; hh < 4; ++hh) rr4[hh] = r_s[w*4 + hh];
      #pragma unroll
      for (int dq = 0; dq < 4; ++dq)
        #pragma unroll
        for (int hh = 0; hh < 4; ++hh) cacc[dq][hh] *= rr4[hh];
      #pragma unroll
      for (int nl = 0; nl < 8; ++nl){
        const f32x4 p = *(const f32x4*)(p_s + nl*16 + w*4);
        const int swn = SWZ(nl);
        #pragma unroll
        for (int dq = 0; dq < 4; ++dq){
          const f32x4 t = *(const f32x4*)(bufc + (size_t)nl*4096 + ((dq*1024 + l*16) ^ swn));
          #pragma unroll
          for (int hh = 0; hh < 4; ++hh)
            cacc[dq][hh] += t * p[hh];
        }
      }
    }
  }

  // ---- epilogue (mzs/logits_s visible since barrier (D) of round 7) ----
  if (tid < 64){
    float s = 0.0f;
    #pragma unroll
    for (int h = 0; h < 16; ++h)
      s += __expf(logits_s[h*64 + tid] - mzs[h*2]) * mzs[h*2 + 1];
    out_mean[(size_t)tb*64 + tid] = s * 0.0625f;
  }
  #pragma unroll
  for (int hh = 0; hh < 4; ++hh){
    const int h = w*4 + hh;
    const float zinv = mzs[h*2 + 1];
    #pragma unroll
    for (int dq = 0; dq < 4; ++dq){
      f32x4 v = cacc[dq][hh];
      uint2 pk;
      pk.x = (u32)f2bf(v.x * zinv) | ((u32)f2bf(v.y * zinv) << 16);
      pk.y = (u32)f2bf(v.z * zinv) | ((u32)f2bf(v.w * zinv) << 16);
      *(uint2*)(ctx + ((size_t)tb*16 + h)*1024 + dq*256 + l*4) = pk;
    }
  }
}

__global__ __launch_bounds__(256) void k_attended(
    const u16* __restrict__ ctx, const u16* __restrict__ WvT, const float* __restrict__ bv,
    float* __restrict__ out_att){
  const int l = threadIdx.x & 63, w = threadIdx.x >> 6;
  const int wm = w & 1, wn = w >> 1, g = l >> 4, li = l & 15;
  const int tb0 = blockIdx.x*64, h = blockIdx.y;
  f32x4 acc[2][2];
  #pragma unroll
  for (int i=0;i<2;++i)
    #pragma unroll
    for (int j=0;j<2;++j) acc[i][j] = (f32x4)0.0f;

  #pragma unroll 4
  for (int kb = 0; kb < 32; ++kb){
    const int k0 = kb*32 + g*8;
    bf16x8 a[2], b[2];
    #pragma unroll
    for (int rt=0;rt<2;++rt)
      a[rt] = *(const bf16x8*)(ctx + ((size_t)(tb0 + wm*32 + rt*16 + li)*16 + h)*1024 + k0);
    #pragma unroll
    for (int ct=0;ct<2;++ct)
      b[ct] = *(const bf16x8*)(WvT + (size_t)(h*64 + wn*32 + ct*16 + li)*1024 + k0);
    #pragma unroll
    for (int rt=0;rt<2;++rt)
      #pragma unroll
      for (int ct=0;ct<2;++ct)
        acc[rt][ct] = MFMA16(a[rt], b[ct], acc[rt][ct]);
  }
  #pragma unroll
  for (int rt=0;rt<2;++rt)
    #pragma unroll
    for (int ct=0;ct<2;++ct)
      #pragma unroll
      for (int r=0;r<4;++r){
        int m = tb0 + wm*32 + rt*16 + g*4 + r;
        int dout = h*64 + wn*32 + ct*16 + li;
        out_att[(size_t)m*1024 + dout] = acc[rt][ct][r] + bv[dout];
      }
}

// ---------------- launch ----------------
extern "C" void kernel_launch(void* const* d_in, const int* in_sizes, int n_in,
                              void* d_out, int out_size, void* d_ws, size_t ws_size,
                              hipStream_t stream){
  const float* qv     = (const float*)d_in[0];
  const float* tokens = (const float*)d_in[1];
  const float* gate   = (const float*)d_in[2];
  const float* Wq     = (const float*)d_in[3];
  const float* bq     = (const float*)d_in[4];
  const float* Wk     = (const float*)d_in[5];
  const float* bk     = (const float*)d_in[6];
  const float* Wv     = (const float*)d_in[7];
  const float* bv     = (const float*)d_in[8];

  char* ws = (char*)d_ws;
  u16*   WqT = (u16*)(ws);                       // 2 MB
  u16*   WkB = (u16*)(ws + (2u<<20));            // 2 MB
  u16*   WvT = (u16*)(ws + (4u<<20));            // 2 MB
  float* qf  = (float*)(ws + (6u<<20));          // 4 MB
  u16*   qb  = (u16*)(ws + (10u<<20));           // 2 MB
  u16*   U   = (u16*)(ws + (12u<<20));           // 32 MB
  u16*   ctxb= (u16*)(ws + (44u<<20));           // 32 MB  (total 76 MB)

  float* out_att    = (float*)d_out;
  float* out_mean   = out_att + 1048576;
  float* out_logits = out_att + 1114112;

  (void)hipFuncSetAttribute((const void*)k_attn,
                            hipFuncAttributeMaxDynamicSharedMemorySize, K3_LDS);
  k_convert <<<dim3(256, 3),    256, 0,      stream>>>(Wq, Wk, Wv, WqT, WkB, WvT);
  k_qproj   <<<dim3(16, 16),    256, 0,      stream>>>(qv, WqT, bq, qf, qb);
  k_umat    <<<dim3(16, 16, 16),256, 0,      stream>>>(qb, WkB, U);
  k_attn    <<<dim3(1024),      256, K3_LDS, stream>>>(tokens, gate, U, qf, bk,
                                                       out_logits, out_mean, ctxb);
  k_attended<<<dim3(16, 16),    256, 0,      stream>>>(ctxb, WvT, bv, out_att);
}